// Round 1
// baseline (398.932 us; speedup 1.0000x reference)
//
#include <hip/hip_runtime.h>
#include <hip/hip_bf16.h>

// Problem constants
#define NB   32
#define CCH  128
#define HH   64
#define WW   64
#define DBOT 512
#define EPS_LN 1e-5f

typedef __attribute__((ext_vector_type(8))) short bf16x8;
typedef __attribute__((ext_vector_type(4))) float f32x4;
typedef __attribute__((ext_vector_type(4))) unsigned int u32x4;

__device__ __forceinline__ float bf2f(unsigned short u) {
    return __uint_as_float(((unsigned)u) << 16);
}
__device__ __forceinline__ unsigned short f2bf(float f) {
    __hip_bfloat16 h = __float2bfloat16(f);
    return *(unsigned short*)&h;
}
__device__ __forceinline__ unsigned pack2(float lo, float hi) {
    __hip_bfloat162 p = __float22bfloat162_rn(make_float2(lo, hi));
    return *(unsigned*)&p;
}
__device__ __forceinline__ float uniform_load(const float* p) {
    // force a workgroup-uniform value into an SGPR
    return __uint_as_float(__builtin_amdgcn_readfirstlane(__float_as_uint(*p)));
}

// ---------------------------------------------------------------------------
// K0: convert pointwise weights fp32 -> bf16 into workspace
// ---------------------------------------------------------------------------
__global__ __launch_bounds__(256) void wcvt_kernel(
    const float* __restrict__ w1, const float* __restrict__ w2,
    __hip_bfloat16* __restrict__ o1, __hip_bfloat16* __restrict__ o2)
{
    int i = blockIdx.x * 256 + threadIdx.x;   // 0 .. 65535
    o1[i] = __float2bfloat16(w1[i]);
    o2[i] = __float2bfloat16(w2[i]);
}

// ---------------------------------------------------------------------------
// K1: depthwise 7x7 conv + bias -> conv_out ([n][h][c][w], bf16)
// one block per (n, c) plane: 64x64 outputs, 256 threads x 16 outputs
// weights in SGPRs (uniform) -> VGPR ~60 -> ~6-8 waves/SIMD
// ---------------------------------------------------------------------------
#define XS 76   // LDS row stride (floats): 4 left pad + 64 data + 8 right pad

__global__ __launch_bounds__(256, 6) void dwconv_kernel(
    const float* __restrict__ x, const float* __restrict__ dw_w,
    const float* __restrict__ dw_b, unsigned short* __restrict__ cout)
{
    __shared__ float xs[64 * XS];

    const int t = threadIdx.x;
    const int n = blockIdx.x >> 7;
    const int c = blockIdx.x & 127;

    const float* xp = x + ((size_t)(n * CCH + c) << 12);

    #pragma unroll
    for (int i = 0; i < 4; ++i) {
        int idx = i * 256 + t;          // float4 index 0..1023
        int r   = idx >> 4;
        int c4  = idx & 15;
        float4 v = ((const float4*)xp)[idx];
        *(float4*)&xs[r * XS + 4 + c4 * 4] = v;
    }
    #pragma unroll
    for (int i = 0; i < 3; ++i) {
        int idx = i * 256 + t;          // 0..767 pad zeroing
        int r   = idx / 12;
        int p   = idx % 12;
        int col = (p < 4) ? p : (p + 64);
        xs[r * XS + col] = 0.0f;
    }

    // block-uniform weights -> SGPRs (frees ~50 VGPRs)
    float wgt[49];
    const float* wp = dw_w + c * 49;
    #pragma unroll
    for (int j = 0; j < 49; ++j) wgt[j] = uniform_load(wp + j);
    const float bias = uniform_load(dw_b + c);

    __syncthreads();

    const int h  = t >> 2;
    const int w0 = (t & 3) << 4;

    float acc[16];
    #pragma unroll
    for (int j = 0; j < 16; ++j) acc[j] = bias;

    #pragma unroll
    for (int kh = 0; kh < 7; ++kh) {
        int hh = h + kh - 3;
        if (hh < 0 || hh >= HH) continue;
        float r[24];
        const float* row = &xs[hh * XS + w0];
        #pragma unroll
        for (int j = 0; j < 6; ++j) *(float4*)&r[j * 4] = *(const float4*)&row[j * 4];
        #pragma unroll
        for (int kw = 0; kw < 7; ++kw)
            #pragma unroll
            for (int j = 0; j < 16; ++j)
                acc[j] = fmaf(r[j + kw + 1], wgt[kh * 7 + kw], acc[j]);
    }

    // pack 16 bf16 into two uint4 without a private union (SROA-safe)
    uint4 s0, s1;
    {
        unsigned p0 = pack2(acc[0],  acc[1]);
        unsigned p1 = pack2(acc[2],  acc[3]);
        unsigned p2 = pack2(acc[4],  acc[5]);
        unsigned p3 = pack2(acc[6],  acc[7]);
        unsigned p4 = pack2(acc[8],  acc[9]);
        unsigned p5 = pack2(acc[10], acc[11]);
        unsigned p6 = pack2(acc[12], acc[13]);
        unsigned p7 = pack2(acc[14], acc[15]);
        s0.x = p0; s0.y = p1; s0.z = p2; s0.w = p3;
        s1.x = p4; s1.y = p5; s1.z = p6; s1.w = p7;
    }
    // layout [n][h][c][w]
    unsigned short* op = cout + ((size_t)((n * 64 + h) * 128 + c) << 6) + w0;
    *(uint4*)op       = s0;
    *(uint4*)(op + 8) = s1;
}

// ---------------------------------------------------------------------------
// K2: LayerNorm + pointwise MLP (bf16 MFMA) + bias + residual, NCHW fp32 out
// one block per (n,h) row: M = 64 positions, K = C = 128. 4 waves, m=16/wave.
//
// Operand-swapped MFMA chain, zero barriers in the GEMM loop:
//   stage1: H^T = W1 . Y^T   (A = W1 rows d=ln; B = af, lane holds Y[pos=ln][k])
//           -> lane holds H[m=ln][d = q*4+r]  (m lane-local!)
//   handoff: relu+pack pairs along d, 8x __shfl within same-ln lane groups
//           -> B2 fragment: lane holds H[m=ln][d = q*8+j]
//   stage2: O^T = W2 . H^T   (A = W2 rows c=ln) -> lane holds O[c=q*4+r][m=ln]
// ---------------------------------------------------------------------------
__global__ __launch_bounds__(256, 4) void mlp_kernel(
    const unsigned short* __restrict__ conv,  // [n][h][c][w] bf16
    const float* __restrict__ gamma,          // 128
    const float* __restrict__ beta,           // 128
    const __hip_bfloat16* __restrict__ w1,    // 512 x 128 (bf16)
    const float* __restrict__ b1,             // 512
    const __hip_bfloat16* __restrict__ w2,    // 128 x 512 (bf16)
    const float* __restrict__ b2,             // 128
    const float* __restrict__ x,              // NCHW fp32
    float* __restrict__ out)                  // NCHW fp32
{
    __shared__ unsigned short xs[CCH * 64];   // staged [c][w] plane (16 KB)
    __shared__ float sPart[2][256];
    __shared__ float sMu[64], sRstd[64];

    const int t    = threadIdx.x;
    const int wave = t >> 6;
    const int lane = t & 63;
    const int q    = lane >> 4;          // 0..3
    const int ln   = lane & 15;          // 0..15
    const int posb = wave << 4;          // wave's 16 positions

    const int n = blockIdx.x >> 6;
    const int h = blockIdx.x & 63;

    // ---- stage plane [c][w] (16 KB contiguous) into LDS ----
    {
        const uint4* src = (const uint4*)(conv + ((size_t)blockIdx.x << 13));
        #pragma unroll
        for (int i = 0; i < 4; ++i) {
            int idx = i * 256 + t;                  // 16B chunk 0..1023
            *(uint4*)&xs[idx * 8] = src[idx];
        }
    }
    __syncthreads();

    // ---- LN stats: thread (cg = t>>6, w = t&63) ----
    {
        const int wI = t & 63, cg = t >> 6;
        float s = 0.f, s2 = 0.f;
        #pragma unroll
        for (int j = 0; j < 32; ++j) {
            float v = bf2f(xs[(cg * 32 + j) * 64 + wI]);
            s += v;
            s2 = fmaf(v, v, s2);
        }
        sPart[0][cg * 64 + wI] = s;
        sPart[1][cg * 64 + wI] = s2;
    }
    __syncthreads();
    if (t < 64) {
        float su = 0.f, sq = 0.f;
        #pragma unroll
        for (int g = 0; g < 4; ++g) { su += sPart[0][g * 64 + t]; sq += sPart[1][g * 64 + t]; }
        float mu  = su * (1.0f / 128.0f);
        float var = sq * (1.0f / 128.0f) - mu * mu;
        sMu[t]   = mu;
        sRstd[t] = 1.0f / sqrtf(var + EPS_LN);
    }
    __syncthreads();

    // ---- normalized Y^T fragments (valid as MFMA B): af[kb], lane holds
    //      Y[pos = posb+ln][c = kb*32 + q*8 + j] ----
    bf16x8 af[4];
    {
        const int pos = posb + ln;
        const float mu = sMu[pos], rs = sRstd[pos];
        #pragma unroll
        for (int kb = 0; kb < 4; ++kb) {
            const int c0 = kb * 32 + q * 8;
            float4 g0  = *(const float4*)(gamma + c0);
            float4 g1  = *(const float4*)(gamma + c0 + 4);
            float4 be0 = *(const float4*)(beta + c0);
            float4 be1 = *(const float4*)(beta + c0 + 4);
            float gv[8] = {g0.x, g0.y, g0.z, g0.w, g1.x, g1.y, g1.z, g1.w};
            float bv[8] = {be0.x, be0.y, be0.z, be0.w, be1.x, be1.y, be1.z, be1.w};
            bf16x8 a;
            #pragma unroll
            for (int j = 0; j < 8; ++j) {
                float v = bf2f(xs[(c0 + j) * 64 + pos]);
                a[j] = (short)f2bf((v - mu) * rs * gv[j] + bv[j]);
            }
            af[kb] = a;
        }
    }

    f32x4 oacc[8];
    #pragma unroll
    for (int ct = 0; ct < 8; ++ct) oacc[ct] = (f32x4){0.f, 0.f, 0.f, 0.f};

    // shuffle sources for the H^T handoff (fixed per lane):
    //   words 0,1 come from lane (q&1)*32 + ln ; words 2,3 from +16
    const int  srcA = ((q & 1) * 32) + ln;
    const int  srcB = srcA + 16;
    const bool hiT  = (q >= 2);          // upper target quarters read tile1

    for (int dc = 0; dc < 4; ++dc) {
        const int d0 = dc * 128;
        #pragma unroll
        for (int kb2 = 0; kb2 < 4; ++kb2) {
            const int db = d0 + kb2 * 32;

            // ---- stage 1: two d-tiles (db..db+15, db+16..db+31), all 128 k ----
            f32x4 h0 = (f32x4){0.f, 0.f, 0.f, 0.f};
            f32x4 h1 = (f32x4){0.f, 0.f, 0.f, 0.f};
            const __hip_bfloat16* w1p = w1 + (size_t)(db + ln) * CCH + q * 8;
            #pragma unroll
            for (int kb = 0; kb < 4; ++kb) {
                bf16x8 a0 = *(const bf16x8*)(w1p + kb * 32);
                bf16x8 a1 = *(const bf16x8*)(w1p + (size_t)16 * CCH + kb * 32);
                h0 = __builtin_amdgcn_mfma_f32_16x16x32_bf16(a0, af[kb], h0, 0, 0, 0);
                h1 = __builtin_amdgcn_mfma_f32_16x16x32_bf16(a1, af[kb], h1, 0, 0, 0);
            }

            // ---- bias + relu + pack bf16 pairs along d ----
            float4 ba = *(const float4*)(b1 + db + q * 4);
            float4 bb = *(const float4*)(b1 + db + 16 + q * 4);
            unsigned P00 = pack2(fmaxf(h0[0] + ba.x, 0.f), fmaxf(h0[1] + ba.y, 0.f));
            unsigned P01 = pack2(fmaxf(h0[2] + ba.z, 0.f), fmaxf(h0[3] + ba.w, 0.f));
            unsigned P10 = pack2(fmaxf(h1[0] + bb.x, 0.f), fmaxf(h1[1] + bb.y, 0.f));
            unsigned P11 = pack2(fmaxf(h1[2] + bb.z, 0.f), fmaxf(h1[3] + bb.w, 0.f));

            // ---- in-register transpose: build B2 fragment via 8 shuffles ----
            unsigned w0lo = __shfl(P00, srcA), w1lo = __shfl(P01, srcA);
            unsigned w2lo = __shfl(P00, srcB), w3lo = __shfl(P01, srcB);
            unsigned w0hi = __shfl(P10, srcA), w1hi = __shfl(P11, srcA);
            unsigned w2hi = __shfl(P10, srcB), w3hi = __shfl(P11, srcB);
            u32x4 bwv;
            bwv.x = hiT ? w0hi : w0lo;
            bwv.y = hiT ? w1hi : w1lo;
            bwv.z = hiT ? w2hi : w2lo;
            bwv.w = hiT ? w3hi : w3lo;
            bf16x8 bfrag = __builtin_bit_cast(bf16x8, bwv);

            // ---- stage 2: O^T += W2_chunk . H^T_chunk (8 c-tiles) ----
            const __hip_bfloat16* w2p = w2 + (size_t)ln * DBOT + db + q * 8;
            #pragma unroll
            for (int ct = 0; ct < 8; ++ct) {
                bf16x8 aw = *(const bf16x8*)(w2p + (size_t)(ct * 16) * DBOT);
                oacc[ct] = __builtin_amdgcn_mfma_f32_16x16x32_bf16(aw, bfrag, oacc[ct], 0, 0, 0);
            }
        }
    }

    // ---- epilogue: lane holds O[c = ct*16+q*4+rr][pos = posb+ln] ----
    const size_t nbase = ((size_t)(n * CCH)) << 12;
    const int hw = (h << 6) + posb + ln;
    #pragma unroll
    for (int ct = 0; ct < 8; ++ct) {
        float4 b2v = *(const float4*)(b2 + ct * 16 + q * 4);
        float bvv[4] = {b2v.x, b2v.y, b2v.z, b2v.w};
        #pragma unroll
        for (int rr = 0; rr < 4; ++rr) {
            int c = ct * 16 + q * 4 + rr;
            size_t idx = nbase + ((size_t)c << 12) + hw;
            out[idx] = oacc[ct][rr] + bvv[rr] + x[idx];
        }
    }
}

// ---------------------------------------------------------------------------
extern "C" void kernel_launch(void* const* d_in, const int* in_sizes, int n_in,
                              void* d_out, int out_size, void* d_ws, size_t ws_size,
                              hipStream_t stream)
{
    const float* x     = (const float*)d_in[0];
    const float* dw_w  = (const float*)d_in[1];
    const float* dw_b  = (const float*)d_in[2];
    const float* gamma = (const float*)d_in[3];
    const float* beta  = (const float*)d_in[4];
    const float* pw1_w = (const float*)d_in[5];
    const float* pw1_b = (const float*)d_in[6];
    const float* pw2_w = (const float*)d_in[7];
    const float* pw2_b = (const float*)d_in[8];
    float* out = (float*)d_out;

    char* ws = (char*)d_ws;
    unsigned short* convb = (unsigned short*)ws;                       // 32 MiB
    __hip_bfloat16* w1b   = (__hip_bfloat16*)(ws + (size_t)33554432);  // 128 KiB
    __hip_bfloat16* w2b   = (__hip_bfloat16*)(ws + (size_t)33554432 + 131072);

    wcvt_kernel<<<256, 256, 0, stream>>>(pw1_w, pw2_w, w1b, w2b);
    dwconv_kernel<<<NB * CCH, 256, 0, stream>>>(x, dw_w, dw_b, convb);
    mlp_kernel<<<NB * HH, 256, 0, stream>>>(convb, gamma, beta, w1b, pw1_b, w2b, pw2_b, x, out);
}

// Round 2
// 318.395 us; speedup vs baseline: 1.2529x; 1.2529x over previous
//
#include <hip/hip_runtime.h>
#include <hip/hip_bf16.h>

// Problem constants
#define NB   32
#define CCH  128
#define HH   64
#define WW   64
#define DBOT 512
#define EPS_LN 1e-5f

typedef __attribute__((ext_vector_type(8))) short bf16x8;
typedef __attribute__((ext_vector_type(4))) float f32x4;

__device__ __forceinline__ float bf2f(unsigned short u) {
    return __uint_as_float(((unsigned)u) << 16);
}
__device__ __forceinline__ unsigned short f2bf(float f) {
    __hip_bfloat16 h = __float2bfloat16(f);
    return *(unsigned short*)&h;
}
__device__ __forceinline__ unsigned pack2(float lo, float hi) {
    __hip_bfloat162 p = __float22bfloat162_rn(make_float2(lo, hi));
    return *(unsigned*)&p;
}
__device__ __forceinline__ float uniform_load(const float* p) {
    return __uint_as_float(__builtin_amdgcn_readfirstlane(__float_as_uint(*p)));
}

// lgkm-only barrier: orders LDS producer->consumer WITHOUT draining vmcnt,
// so global/L2 prefetches and the global_load_lds DMA stay in flight.
#define BAR_LGKM() do { \
    asm volatile("s_waitcnt lgkmcnt(0)" ::: "memory"); \
    __builtin_amdgcn_s_barrier(); } while (0)
// full drain barrier (used once per row, before consuming the DMA'd plane)
#define BAR_VM() do { \
    asm volatile("s_waitcnt vmcnt(0) lgkmcnt(0)" ::: "memory"); \
    __builtin_amdgcn_s_barrier(); } while (0)

// ---------------------------------------------------------------------------
// K0: convert pointwise weights fp32 -> bf16 into workspace
// ---------------------------------------------------------------------------
__global__ __launch_bounds__(256) void wcvt_kernel(
    const float* __restrict__ w1, const float* __restrict__ w2,
    __hip_bfloat16* __restrict__ o1, __hip_bfloat16* __restrict__ o2)
{
    int i = blockIdx.x * 256 + threadIdx.x;   // 0 .. 65535
    o1[i] = __float2bfloat16(w1[i]);
    o2[i] = __float2bfloat16(w2[i]);
}

// ---------------------------------------------------------------------------
// K1: depthwise 7x7 conv + bias -> conv_out ([n][h][c][w], bf16)
// Persistent: 1024 blocks x 4 planes, double-buffered LDS, next-plane
// prefetch (global->reg) issued before compute so 16 KB/block stays in
// flight under the ~2000-cycle FMA phase. One lgkm barrier per plane.
// ---------------------------------------------------------------------------
#define XS 76   // LDS row stride (floats): 4 left pad + 64 data + 8 right pad

__global__ __launch_bounds__(256, 4) void dwconv_kernel(
    const float* __restrict__ x, const float* __restrict__ dw_w,
    const float* __restrict__ dw_b, unsigned short* __restrict__ cout)
{
    __shared__ float xs2[2][64 * XS];

    const int t = threadIdx.x;

    // zero halo pads of BOTH buffers (data writes never touch them)
    #pragma unroll
    for (int b = 0; b < 2; ++b) {
        #pragma unroll
        for (int i = 0; i < 3; ++i) {
            int idx = i * 256 + t;          // 0..767
            int r   = idx / 12;
            int p   = idx % 12;
            int col = (p < 4) ? p : (p + 64);
            xs2[b][r * XS + col] = 0.0f;
        }
    }

    // prologue: plane 0 -> regs -> buf 0
    float4 st[4];
    {
        const int pid0 = blockIdx.x * 4;
        const float* xp = x + ((size_t)pid0 << 12);
        #pragma unroll
        for (int i = 0; i < 4; ++i) st[i] = ((const float4*)xp)[i * 256 + t];
        #pragma unroll
        for (int i = 0; i < 4; ++i) {
            int idx = i * 256 + t;
            int r   = idx >> 4;
            int c4  = idx & 15;
            *(float4*)&xs2[0][r * XS + 4 + c4 * 4] = st[i];
        }
    }
    BAR_LGKM();

    const int h  = t >> 2;
    const int w0 = (t & 3) << 4;

    for (int k = 0; k < 4; ++k) {
        const int pid = blockIdx.x * 4 + k;
        const int n   = pid >> 7;
        const int c   = pid & 127;
        const int cur = k & 1;

        // issue next plane's loads FIRST (longest latency, hidden by compute)
        if (k < 3) {
            const float* xn = x + ((size_t)(pid + 1) << 12);
            #pragma unroll
            for (int i = 0; i < 4; ++i) st[i] = ((const float4*)xn)[i * 256 + t];
        }

        // block-uniform weights -> SGPRs
        float wgt[49];
        const float* wp = dw_w + c * 49;
        #pragma unroll
        for (int j = 0; j < 49; ++j) wgt[j] = uniform_load(wp + j);
        const float bias = uniform_load(dw_b + c);

        float acc[16];
        #pragma unroll
        for (int j = 0; j < 16; ++j) acc[j] = bias;

        const float* xsb = xs2[cur];
        #pragma unroll
        for (int kh = 0; kh < 7; ++kh) {
            int hh = h + kh - 3;
            if (hh < 0 || hh >= HH) continue;
            float r[24];
            const float* row = &xsb[hh * XS + w0];
            #pragma unroll
            for (int j = 0; j < 6; ++j) *(float4*)&r[j * 4] = *(const float4*)&row[j * 4];
            #pragma unroll
            for (int kw = 0; kw < 7; ++kw)
                #pragma unroll
                for (int j = 0; j < 16; ++j)
                    acc[j] = fmaf(r[j + kw + 1], wgt[kh * 7 + kw], acc[j]);
        }

        // pack 16 bf16 into two uint4 (SROA-safe)
        uint4 s0, s1;
        {
            unsigned p0 = pack2(acc[0],  acc[1]);
            unsigned p1 = pack2(acc[2],  acc[3]);
            unsigned p2 = pack2(acc[4],  acc[5]);
            unsigned p3 = pack2(acc[6],  acc[7]);
            unsigned p4 = pack2(acc[8],  acc[9]);
            unsigned p5 = pack2(acc[10], acc[11]);
            unsigned p6 = pack2(acc[12], acc[13]);
            unsigned p7 = pack2(acc[14], acc[15]);
            s0.x = p0; s0.y = p1; s0.z = p2; s0.w = p3;
            s1.x = p4; s1.y = p5; s1.z = p6; s1.w = p7;
        }
        unsigned short* op = cout + ((size_t)((n * 64 + h) * 128 + c) << 6) + w0;
        *(uint4*)op       = s0;
        *(uint4*)(op + 8) = s1;

        // hand staged regs to the other buffer; one barrier per plane
        if (k < 3) {
            #pragma unroll
            for (int i = 0; i < 4; ++i) {
                int idx = i * 256 + t;
                int r   = idx >> 4;
                int c4  = idx & 15;
                *(float4*)&xs2[cur ^ 1][r * XS + 4 + c4 * 4] = st[i];
            }
            BAR_LGKM();
        }
    }
}

// ---------------------------------------------------------------------------
// K2: LayerNorm + pointwise MLP (bf16 MFMA) + bias + residual, NCHW fp32 out
// Round-0 verified structure (fragments, layouts, loop order identical).
// Persistent: 1024 blocks x 2 rows. Next row's conv plane arrives via
// global_load_lds DMA (issued inside row 0's dc loop); all dc-loop barriers
// are lgkm-only so W1/W2 prefetches and the DMA survive across them.
// ---------------------------------------------------------------------------
#define HS 136   // sH row stride in shorts (272 B = 17 x 16 B)

__global__ __launch_bounds__(256, 4) void mlp_kernel(
    const unsigned short* __restrict__ conv,  // [n][h][c][w] bf16
    const float* __restrict__ gamma,          // 128
    const float* __restrict__ beta,           // 128
    const __hip_bfloat16* __restrict__ w1,    // 512 x 128 (bf16)
    const float* __restrict__ b1,             // 512
    const __hip_bfloat16* __restrict__ w2,    // 128 x 512 (bf16)
    const float* __restrict__ b2,             // 128
    const float* __restrict__ x,              // NCHW fp32
    float* __restrict__ out)                  // NCHW fp32
{
    __shared__ unsigned short xs[CCH * 64];   // staged [c][w] plane (16 KB)
    __shared__ unsigned short hbuf[64 * HS];  // H chunk [pos][d] (17 KB)
    __shared__ float sPart[2][256];
    __shared__ float sMu[64], sRstd[64];

    const int t    = threadIdx.x;
    const int wave = t >> 6;
    const int lane = t & 63;
    const int q    = lane >> 4;          // 0..3
    const int ln   = lane & 15;          // 0..15
    const int wm   = (wave >> 1) * 32;   // wave M offset (0/32)
    const int wn   = (wave & 1) * 64;    // wave N offset (0/64)

    // prologue: DMA row 0's plane into xs (linear [c][w], 1024 x 16B chunks)
    {
        const char* src = (const char*)conv + (((size_t)(blockIdx.x * 2)) << 14);
        #pragma unroll
        for (int i = 0; i < 4; ++i) {
            int cb = (wave * 4 + i) * 64;                 // chunk base for this wave
            __builtin_amdgcn_global_load_lds(
                (const __attribute__((address_space(1))) void*)(src + (size_t)(cb + lane) * 16),
                (__attribute__((address_space(3))) void*)(&xs[(wave * 4 + i) * 512]),
                16, 0, 0);
        }
    }
    BAR_VM();

    for (int k = 0; k < 2; ++k) {
        const int rid = blockIdx.x * 2 + k;
        const int n   = rid >> 6;
        const int h   = rid & 63;

        // ---- LN stats ----
        {
            const int wI = t & 63, cg = t >> 6;
            float s = 0.f, s2 = 0.f;
            #pragma unroll
            for (int j = 0; j < 32; ++j) {
                float v = bf2f(xs[(cg * 32 + j) * 64 + wI]);
                s += v;
                s2 = fmaf(v, v, s2);
            }
            sPart[0][cg * 64 + wI] = s;
            sPart[1][cg * 64 + wI] = s2;
        }
        BAR_LGKM();
        if (t < 64) {
            float su = 0.f, sq = 0.f;
            #pragma unroll
            for (int g = 0; g < 4; ++g) { su += sPart[0][g * 64 + t]; sq += sPart[1][g * 64 + t]; }
            float mu  = su * (1.0f / 128.0f);
            float var = sq * (1.0f / 128.0f) - mu * mu;
            sMu[t]   = mu;
            sRstd[t] = 1.0f / sqrtf(var + EPS_LN);
        }
        BAR_LGKM();

        // ---- normalized A-fragments in registers: A[m=pos][k=c] ----
        bf16x8 af[2][4];
        #pragma unroll
        for (int mt = 0; mt < 2; ++mt) {
            const int pos = wm + mt * 16 + ln;
            const float mu = sMu[pos], rs = sRstd[pos];
            #pragma unroll
            for (int kb = 0; kb < 4; ++kb) {
                const int c0 = kb * 32 + q * 8;
                float4 g0  = *(const float4*)(gamma + c0);
                float4 g1  = *(const float4*)(gamma + c0 + 4);
                float4 be0 = *(const float4*)(beta + c0);
                float4 be1 = *(const float4*)(beta + c0 + 4);
                float gv[8] = {g0.x, g0.y, g0.z, g0.w, g1.x, g1.y, g1.z, g1.w};
                float bv[8] = {be0.x, be0.y, be0.z, be0.w, be1.x, be1.y, be1.z, be1.w};
                bf16x8 a;
                #pragma unroll
                for (int j = 0; j < 8; ++j) {
                    float v = bf2f(xs[(c0 + j) * 64 + pos]);
                    float r = (v - mu) * rs * gv[j] + bv[j];
                    a[j] = (short)f2bf(r);
                }
                af[mt][kb] = a;
            }
        }

        f32x4 oacc[2][4];
        #pragma unroll
        for (int mt = 0; mt < 2; ++mt)
            #pragma unroll
            for (int ct = 0; ct < 4; ++ct) oacc[mt][ct] = (f32x4){0.f, 0.f, 0.f, 0.f};

        for (int dc = 0; dc < 4; ++dc) {
            const int d0 = dc * 128;

            // stage 1: Hc = Y @ W1^T (A from regs, B from global/L2)
            f32x4 hacc[2][4];
            #pragma unroll
            for (int mt = 0; mt < 2; ++mt)
                #pragma unroll
                for (int dt = 0; dt < 4; ++dt) hacc[mt][dt] = (f32x4){0.f, 0.f, 0.f, 0.f};

            #pragma unroll
            for (int kb = 0; kb < 4; ++kb) {
                bf16x8 bw[4];
                #pragma unroll
                for (int dt = 0; dt < 4; ++dt) {
                    int d = d0 + wn + dt * 16 + ln;
                    bw[dt] = *(const bf16x8*)(w1 + (size_t)d * 128 + kb * 32 + q * 8);
                }
                #pragma unroll
                for (int mt = 0; mt < 2; ++mt)
                    #pragma unroll
                    for (int dt = 0; dt < 4; ++dt)
                        hacc[mt][dt] = __builtin_amdgcn_mfma_f32_16x16x32_bf16(
                            af[mt][kb], bw[dt], hacc[mt][dt], 0, 0, 0);
            }

            BAR_LGKM();   // prev readers of hbuf done (and A-build xs reads done)

            // once per block: kick off next row's plane DMA (xs fully consumed)
            if (dc == 0 && k == 0) {
                const char* src = (const char*)conv + (((size_t)(blockIdx.x * 2 + 1)) << 14);
                #pragma unroll
                for (int i = 0; i < 4; ++i) {
                    int cb = (wave * 4 + i) * 64;
                    __builtin_amdgcn_global_load_lds(
                        (const __attribute__((address_space(1))) void*)(src + (size_t)(cb + lane) * 16),
                        (__attribute__((address_space(3))) void*)(&xs[(wave * 4 + i) * 512]),
                        16, 0, 0);
                }
            }

            // bias + relu + bf16 -> hbuf
            #pragma unroll
            for (int dt = 0; dt < 4; ++dt) {
                const int dl = wn + dt * 16 + ln;
                const float b1v = b1[d0 + dl];
                #pragma unroll
                for (int mt = 0; mt < 2; ++mt) {
                    #pragma unroll
                    for (int r = 0; r < 4; ++r) {
                        float v = fmaxf(hacc[mt][dt][r] + b1v, 0.0f);
                        hbuf[(wm + mt * 16 + q * 4 + r) * HS + dl] = f2bf(v);
                    }
                }
            }
            BAR_LGKM();

            // stage 2: O += H @ W2_chunk^T
            #pragma unroll
            for (int kb = 0; kb < 4; ++kb) {
                bf16x8 ah[2];
                #pragma unroll
                for (int mt = 0; mt < 2; ++mt)
                    ah[mt] = *(const bf16x8*)&hbuf[(wm + mt * 16 + ln) * HS + kb * 32 + q * 8];
                bf16x8 bw2[4];
                #pragma unroll
                for (int ct = 0; ct < 4; ++ct) {
                    int c = wn + ct * 16 + ln;
                    bw2[ct] = *(const bf16x8*)(w2 + (size_t)c * DBOT + d0 + kb * 32 + q * 8);
                }
                #pragma unroll
                for (int mt = 0; mt < 2; ++mt)
                    #pragma unroll
                    for (int ct = 0; ct < 4; ++ct)
                        oacc[mt][ct] = __builtin_amdgcn_mfma_f32_16x16x32_bf16(
                            ah[mt], bw2[ct], oacc[mt][ct], 0, 0, 0);
            }
        }

        // ---- epilogue: direct float4 stores, out = O + b2 + x (NCHW) ----
        #pragma unroll
        for (int ct = 0; ct < 4; ++ct) {
            const int c = wn + ct * 16 + ln;
            const float b2v = b2[c];
            #pragma unroll
            for (int mt = 0; mt < 2; ++mt) {
                size_t base = ((size_t)(n * CCH + c) << 12) + (h << 6) + wm + mt * 16 + q * 4;
                float4 xr = *(const float4*)(x + base);
                float4 o;
                o.x = oacc[mt][ct][0] + b2v + xr.x;
                o.y = oacc[mt][ct][1] + b2v + xr.y;
                o.z = oacc[mt][ct][2] + b2v + xr.z;
                o.w = oacc[mt][ct][3] + b2v + xr.w;
                *(float4*)(out + base) = o;
            }
        }

        if (k == 0) BAR_VM();   // DMA'd plane (and stray VMEM) complete before next stats
    }
}

// ---------------------------------------------------------------------------
extern "C" void kernel_launch(void* const* d_in, const int* in_sizes, int n_in,
                              void* d_out, int out_size, void* d_ws, size_t ws_size,
                              hipStream_t stream)
{
    const float* x     = (const float*)d_in[0];
    const float* dw_w  = (const float*)d_in[1];
    const float* dw_b  = (const float*)d_in[2];
    const float* gamma = (const float*)d_in[3];
    const float* beta  = (const float*)d_in[4];
    const float* pw1_w = (const float*)d_in[5];
    const float* pw1_b = (const float*)d_in[6];
    const float* pw2_w = (const float*)d_in[7];
    const float* pw2_b = (const float*)d_in[8];
    float* out = (float*)d_out;

    char* ws = (char*)d_ws;
    unsigned short* convb = (unsigned short*)ws;                       // 32 MiB
    __hip_bfloat16* w1b   = (__hip_bfloat16*)(ws + (size_t)33554432);  // 128 KiB
    __hip_bfloat16* w2b   = (__hip_bfloat16*)(ws + (size_t)33554432 + 131072);

    wcvt_kernel<<<256, 256, 0, stream>>>(pw1_w, pw2_w, w1b, w2b);
    dwconv_kernel<<<1024, 256, 0, stream>>>(x, dw_w, dw_b, convb);
    mlp_kernel<<<1024, 256, 0, stream>>>(convb, gamma, beta, w1b, pw1_b, w2b, pw2_b, x, out);
}

// Round 6
// 287.475 us; speedup vs baseline: 1.3877x; 1.1076x over previous
//
#include <hip/hip_runtime.h>
#include <hip/hip_bf16.h>

// Problem constants
#define NB   32
#define CCH  128
#define HH   64
#define WW   64
#define DBOT 512
#define EPS_LN 1e-5f

typedef __attribute__((ext_vector_type(8))) short bf16x8;
typedef __attribute__((ext_vector_type(4))) float f32x4;

__device__ __forceinline__ float bf2f(unsigned short u) {
    return __uint_as_float(((unsigned)u) << 16);
}
__device__ __forceinline__ unsigned short f2bf(float f) {
    __hip_bfloat16 h = __float2bfloat16(f);
    return *(unsigned short*)&h;
}
__device__ __forceinline__ float uniform_load(const float* p) {
    // block-uniform value -> SGPR
    return __uint_as_float(__builtin_amdgcn_readfirstlane(__float_as_uint(*p)));
}

// lgkm-only barrier: orders LDS producer->consumer WITHOUT draining vmcnt,
// so W1/W2 L2 prefetches survive across dc-loop phases. Correctness-verified
// pattern (r2 passed with it). No barrier in mlp protects a global hazard.
#define BAR_LGKM() do { \
    asm volatile("s_waitcnt lgkmcnt(0)" ::: "memory"); \
    __builtin_amdgcn_s_barrier(); } while (0)

// ---------------------------------------------------------------------------
// K0: convert pointwise weights fp32 -> bf16 into workspace
// ---------------------------------------------------------------------------
__global__ __launch_bounds__(256) void wcvt_kernel(
    const float* __restrict__ w1, const float* __restrict__ w2,
    __hip_bfloat16* __restrict__ o1, __hip_bfloat16* __restrict__ o2)
{
    int i = blockIdx.x * 256 + threadIdx.x;   // 0 .. 65535
    o1[i] = __float2bfloat16(w1[i]);
    o2[i] = __float2bfloat16(w2[i]);
}

// ---------------------------------------------------------------------------
// K1: depthwise 7x7 conv + bias -> conv_out ([n][h][c][w], bf16)
// r0 structure; weights moved to SGPRs per-kh (7 live at a time) to cut
// VGPR ~110 -> ~65 and double resident waves (latency-bound kernel).
// ---------------------------------------------------------------------------
#define XS 76   // LDS row stride (floats): 4 left pad + 64 data + 8 right pad

__global__ __launch_bounds__(256, 6) void dwconv_kernel(
    const float* __restrict__ x, const float* __restrict__ dw_w,
    const float* __restrict__ dw_b, unsigned short* __restrict__ cout)
{
    __shared__ float xs[64 * XS];

    const int t = threadIdx.x;
    const int n = blockIdx.x >> 7;
    const int c = blockIdx.x & 127;

    const float* xp = x + ((size_t)(n * CCH + c) << 12);

    #pragma unroll
    for (int i = 0; i < 4; ++i) {
        int idx = i * 256 + t;          // float4 index 0..1023
        int r   = idx >> 4;
        int c4  = idx & 15;
        float4 v = ((const float4*)xp)[idx];
        *(float4*)&xs[r * XS + 4 + c4 * 4] = v;
    }
    #pragma unroll
    for (int i = 0; i < 3; ++i) {
        int idx = i * 256 + t;          // 0..767 pad zeroing
        int r   = idx / 12;
        int p   = idx % 12;
        int col = (p < 4) ? p : (p + 64);
        xs[r * XS + col] = 0.0f;
    }

    const float* wp  = dw_w + c * 49;
    const float bias = uniform_load(dw_b + c);

    __syncthreads();

    const int h  = t >> 2;
    const int w0 = (t & 3) << 4;

    float acc[16];
    #pragma unroll
    for (int j = 0; j < 16; ++j) acc[j] = bias;

    #pragma unroll
    for (int kh = 0; kh < 7; ++kh) {
        int hh = h + kh - 3;
        if (hh < 0 || hh >= HH) continue;
        // 7 block-uniform weights -> SGPRs (short live range)
        float wk[7];
        #pragma unroll
        for (int i = 0; i < 7; ++i) wk[i] = uniform_load(wp + kh * 7 + i);
        float r[24];
        const float* row = &xs[hh * XS + w0];
        #pragma unroll
        for (int j = 0; j < 6; ++j) *(float4*)&r[j * 4] = *(const float4*)&row[j * 4];
        #pragma unroll
        for (int kw = 0; kw < 7; ++kw)
            #pragma unroll
            for (int j = 0; j < 16; ++j)
                acc[j] = fmaf(r[j + kw + 1], wk[kw], acc[j]);
    }

    // pack 16 bf16 into two uint4 without a private union (SROA-safe)
    uint4 s0, s1;
    {
        __hip_bfloat162 p0 = __float22bfloat162_rn(make_float2(acc[0],  acc[1]));
        __hip_bfloat162 p1 = __float22bfloat162_rn(make_float2(acc[2],  acc[3]));
        __hip_bfloat162 p2 = __float22bfloat162_rn(make_float2(acc[4],  acc[5]));
        __hip_bfloat162 p3 = __float22bfloat162_rn(make_float2(acc[6],  acc[7]));
        __hip_bfloat162 p4 = __float22bfloat162_rn(make_float2(acc[8],  acc[9]));
        __hip_bfloat162 p5 = __float22bfloat162_rn(make_float2(acc[10], acc[11]));
        __hip_bfloat162 p6 = __float22bfloat162_rn(make_float2(acc[12], acc[13]));
        __hip_bfloat162 p7 = __float22bfloat162_rn(make_float2(acc[14], acc[15]));
        s0.x = *(unsigned*)&p0; s0.y = *(unsigned*)&p1;
        s0.z = *(unsigned*)&p2; s0.w = *(unsigned*)&p3;
        s1.x = *(unsigned*)&p4; s1.y = *(unsigned*)&p5;
        s1.z = *(unsigned*)&p6; s1.w = *(unsigned*)&p7;
    }
    // layout [n][h][c][w]
    unsigned short* op = cout + ((size_t)((n * 64 + h) * 128 + c) << 6) + w0;
    *(uint4*)op       = s0;
    *(uint4*)(op + 8) = s1;
}

// ---------------------------------------------------------------------------
// K2: LayerNorm + pointwise MLP (bf16 MFMA) + bias + residual, NCHW fp32 out
// r0 structure verbatim; all barriers are lgkm-only (no vmcnt drain) so
// W1/W2 prefetches stay in flight across the dc loop (r2-verified pattern).
// ---------------------------------------------------------------------------
#define HS 136   // sH row stride in shorts (272 B = 17 x 16 B)

__global__ __launch_bounds__(256, 4) void mlp_kernel(
    const unsigned short* __restrict__ conv,  // [n][h][c][w] bf16
    const float* __restrict__ gamma,          // 128
    const float* __restrict__ beta,           // 128
    const __hip_bfloat16* __restrict__ w1,    // 512 x 128 (bf16)
    const float* __restrict__ b1,             // 512
    const __hip_bfloat16* __restrict__ w2,    // 128 x 512 (bf16)
    const float* __restrict__ b2,             // 128
    const float* __restrict__ x,              // NCHW fp32
    float* __restrict__ out)                  // NCHW fp32
{
    __shared__ union {
        unsigned short xs[CCH * 64];   // staged [c][w] plane (16 KB)
        unsigned short h[64 * HS];     // H chunk [pos][d] (17 KB)
    } u;
    __shared__ float sPart[2][256];
    __shared__ float sMu[64], sRstd[64];

    const int t    = threadIdx.x;
    const int wave = t >> 6;
    const int lane = t & 63;
    const int q    = lane >> 4;          // 0..3
    const int ln   = lane & 15;          // 0..15
    const int wm   = (wave >> 1) * 32;   // wave M offset (0/32)
    const int wn   = (wave & 1) * 64;    // wave N offset (0/64)

    const int n = blockIdx.x >> 6;
    const int h = blockIdx.x & 63;

    // ---- stage plane [c][w] (16 KB contiguous) into LDS ----
    {
        const uint4* src = (const uint4*)(conv + ((size_t)blockIdx.x << 13));
        #pragma unroll
        for (int i = 0; i < 4; ++i) {
            int idx = i * 256 + t;                  // 16B chunk 0..1023
            uint4 v = src[idx];
            *(uint4*)&u.xs[idx * 8] = v;
        }
    }
    BAR_LGKM();   // ds_writes carry the vmcnt data-dep; lgkm orders the LDS

    // ---- LN stats: thread (cg = t>>6, w = t&63) ----
    {
        const int wI = t & 63, cg = t >> 6;
        float s = 0.f, s2 = 0.f;
        #pragma unroll
        for (int j = 0; j < 32; ++j) {
            float v = bf2f(u.xs[(cg * 32 + j) * 64 + wI]);
            s += v;
            s2 = fmaf(v, v, s2);
        }
        sPart[0][cg * 64 + wI] = s;
        sPart[1][cg * 64 + wI] = s2;
    }
    BAR_LGKM();
    if (t < 64) {
        float su = 0.f, sq = 0.f;
        #pragma unroll
        for (int g = 0; g < 4; ++g) { su += sPart[0][g * 64 + t]; sq += sPart[1][g * 64 + t]; }
        float mu  = su * (1.0f / 128.0f);
        float var = sq * (1.0f / 128.0f) - mu * mu;
        sMu[t]   = mu;
        sRstd[t] = 1.0f / sqrtf(var + EPS_LN);
    }
    BAR_LGKM();

    // ---- build normalized A-fragments in registers: A[m=pos][k=c] ----
    bf16x8 af[2][4];
    #pragma unroll
    for (int mt = 0; mt < 2; ++mt) {
        const int pos = wm + mt * 16 + ln;
        const float mu = sMu[pos], rs = sRstd[pos];
        #pragma unroll
        for (int kb = 0; kb < 4; ++kb) {
            const int c0 = kb * 32 + q * 8;
            float4 g0  = *(const float4*)(gamma + c0);
            float4 g1  = *(const float4*)(gamma + c0 + 4);
            float4 be0 = *(const float4*)(beta + c0);
            float4 be1 = *(const float4*)(beta + c0 + 4);
            float gv[8] = {g0.x, g0.y, g0.z, g0.w, g1.x, g1.y, g1.z, g1.w};
            float bv[8] = {be0.x, be0.y, be0.z, be0.w, be1.x, be1.y, be1.z, be1.w};
            bf16x8 a;
            #pragma unroll
            for (int j = 0; j < 8; ++j) {
                float v = bf2f(u.xs[(c0 + j) * 64 + pos]);
                float r = (v - mu) * rs * gv[j] + bv[j];
                a[j] = (short)f2bf(r);
            }
            af[mt][kb] = a;
        }
    }

    f32x4 oacc[2][4];
    #pragma unroll
    for (int mt = 0; mt < 2; ++mt)
        #pragma unroll
        for (int ct = 0; ct < 4; ++ct) oacc[mt][ct] = (f32x4){0.f, 0.f, 0.f, 0.f};

    for (int dc = 0; dc < 4; ++dc) {
        const int d0 = dc * 128;

        // stage 1: Hc = Y @ W1^T (A from regs, B from global/L2)
        f32x4 hacc[2][4];
        #pragma unroll
        for (int mt = 0; mt < 2; ++mt)
            #pragma unroll
            for (int dt = 0; dt < 4; ++dt) hacc[mt][dt] = (f32x4){0.f, 0.f, 0.f, 0.f};

        #pragma unroll
        for (int kb = 0; kb < 4; ++kb) {
            bf16x8 bw[4];
            #pragma unroll
            for (int dt = 0; dt < 4; ++dt) {
                int d = d0 + wn + dt * 16 + ln;
                bw[dt] = *(const bf16x8*)(w1 + (size_t)d * 128 + kb * 32 + q * 8);
            }
            #pragma unroll
            for (int mt = 0; mt < 2; ++mt)
                #pragma unroll
                for (int dt = 0; dt < 4; ++dt)
                    hacc[mt][dt] = __builtin_amdgcn_mfma_f32_16x16x32_bf16(
                        af[mt][kb], bw[dt], hacc[mt][dt], 0, 0, 0);
        }

        BAR_LGKM();   // prev readers of u (xs A-build or stage2) done

        // bias + relu + bf16 -> sH
        #pragma unroll
        for (int dt = 0; dt < 4; ++dt) {
            const int dl = wn + dt * 16 + ln;
            const float b1v = b1[d0 + dl];
            #pragma unroll
            for (int mt = 0; mt < 2; ++mt) {
                #pragma unroll
                for (int r = 0; r < 4; ++r) {
                    float v = fmaxf(hacc[mt][dt][r] + b1v, 0.0f);
                    u.h[(wm + mt * 16 + q * 4 + r) * HS + dl] = f2bf(v);
                }
            }
        }
        BAR_LGKM();

        // stage 2: O += H @ W2_chunk^T
        #pragma unroll
        for (int kb = 0; kb < 4; ++kb) {
            bf16x8 ah[2];
            #pragma unroll
            for (int mt = 0; mt < 2; ++mt)
                ah[mt] = *(const bf16x8*)&u.h[(wm + mt * 16 + ln) * HS + kb * 32 + q * 8];
            bf16x8 bw2[4];
            #pragma unroll
            for (int ct = 0; ct < 4; ++ct) {
                int c = wn + ct * 16 + ln;
                bw2[ct] = *(const bf16x8*)(w2 + (size_t)c * DBOT + d0 + kb * 32 + q * 8);
            }
            #pragma unroll
            for (int mt = 0; mt < 2; ++mt)
                #pragma unroll
                for (int ct = 0; ct < 4; ++ct)
                    oacc[mt][ct] = __builtin_amdgcn_mfma_f32_16x16x32_bf16(
                        ah[mt], bw2[ct], oacc[mt][ct], 0, 0, 0);
        }
    }

    // ---- epilogue: direct float4 stores, out = O + b2 + x (NCHW) ----
    #pragma unroll
    for (int ct = 0; ct < 4; ++ct) {
        const int c = wn + ct * 16 + ln;
        const float b2v = b2[c];
        #pragma unroll
        for (int mt = 0; mt < 2; ++mt) {
            size_t base = ((size_t)(n * CCH + c) << 12) + (h << 6) + wm + mt * 16 + q * 4;
            float4 xr = *(const float4*)(x + base);
            float4 o;
            o.x = oacc[mt][ct][0] + b2v + xr.x;
            o.y = oacc[mt][ct][1] + b2v + xr.y;
            o.z = oacc[mt][ct][2] + b2v + xr.z;
            o.w = oacc[mt][ct][3] + b2v + xr.w;
            *(float4*)(out + base) = o;
        }
    }
}

// ---------------------------------------------------------------------------
extern "C" void kernel_launch(void* const* d_in, const int* in_sizes, int n_in,
                              void* d_out, int out_size, void* d_ws, size_t ws_size,
                              hipStream_t stream)
{
    const float* x     = (const float*)d_in[0];
    const float* dw_w  = (const float*)d_in[1];
    const float* dw_b  = (const float*)d_in[2];
    const float* gamma = (const float*)d_in[3];
    const float* beta  = (const float*)d_in[4];
    const float* pw1_w = (const float*)d_in[5];
    const float* pw1_b = (const float*)d_in[6];
    const float* pw2_w = (const float*)d_in[7];
    const float* pw2_b = (const float*)d_in[8];
    float* out = (float*)d_out;

    char* ws = (char*)d_ws;
    unsigned short* convb = (unsigned short*)ws;                       // 32 MiB
    __hip_bfloat16* w1b   = (__hip_bfloat16*)(ws + (size_t)33554432);  // 128 KiB
    __hip_bfloat16* w2b   = (__hip_bfloat16*)(ws + (size_t)33554432 + 131072);

    wcvt_kernel<<<256, 256, 0, stream>>>(pw1_w, pw2_w, w1b, w2b);
    dwconv_kernel<<<NB * CCH, 256, 0, stream>>>(x, dw_w, dw_b, convb);
    mlp_kernel<<<NB * HH, 256, 0, stream>>>(convb, gamma, beta, w1b, pw1_b, w2b, pw2_b, x, out);
}

// Round 7
// 286.755 us; speedup vs baseline: 1.3912x; 1.0025x over previous
//
#include <hip/hip_runtime.h>
#include <hip/hip_bf16.h>

// Problem constants
#define NB   32
#define CCH  128
#define HH   64
#define WW   64
#define DBOT 512
#define EPS_LN 1e-5f

typedef __attribute__((ext_vector_type(8))) short bf16x8;
typedef __attribute__((ext_vector_type(4))) float f32x4;

__device__ __forceinline__ float bf2f(unsigned short u) {
    return __uint_as_float(((unsigned)u) << 16);
}
__device__ __forceinline__ unsigned short f2bf(float f) {
    __hip_bfloat16 h = __float2bfloat16(f);
    return *(unsigned short*)&h;
}
__device__ __forceinline__ float uniform_load(const float* p) {
    // block-uniform value -> SGPR
    return __uint_as_float(__builtin_amdgcn_readfirstlane(__float_as_uint(*p)));
}

// lgkm-only barrier (r6-verified): orders LDS producer->consumer without
// draining vmcnt.
#define BAR_LGKM() do { \
    asm volatile("s_waitcnt lgkmcnt(0)" ::: "memory"); \
    __builtin_amdgcn_s_barrier(); } while (0)

// ---------------------------------------------------------------------------
// K0: convert pointwise weights fp32 -> bf16 into workspace
// ---------------------------------------------------------------------------
__global__ __launch_bounds__(256) void wcvt_kernel(
    const float* __restrict__ w1, const float* __restrict__ w2,
    __hip_bfloat16* __restrict__ o1, __hip_bfloat16* __restrict__ o2)
{
    int i = blockIdx.x * 256 + threadIdx.x;   // 0 .. 65535
    o1[i] = __float2bfloat16(w1[i]);
    o2[i] = __float2bfloat16(w2[i]);
}

// ---------------------------------------------------------------------------
// K1: depthwise 7x7 conv + bias -> conv_out ([n][h][c][w], bf16)
// r6 structure. NEW: XCD-contiguous block swizzle — XCD k owns n in
// [4k,4k+4) x all c, so consecutive-c blocks (which write ADJACENT 128-B
// conv chunks) share one L2 and evictions are dense full lines.
// ---------------------------------------------------------------------------
#define XS 76   // LDS row stride (floats): 4 left pad + 64 data + 8 right pad

__global__ __launch_bounds__(256, 6) void dwconv_kernel(
    const float* __restrict__ x, const float* __restrict__ dw_w,
    const float* __restrict__ dw_b, unsigned short* __restrict__ cout)
{
    __shared__ float xs[64 * XS];

    const int t = threadIdx.x;
    // bijective XCD swizzle: 4096 blocks = 8 XCDs x 512 contiguous planes
    const int pid = ((blockIdx.x & 7) << 9) | (blockIdx.x >> 3);
    const int n = pid >> 7;
    const int c = pid & 127;

    const float* xp = x + ((size_t)(n * CCH + c) << 12);

    #pragma unroll
    for (int i = 0; i < 4; ++i) {
        int idx = i * 256 + t;          // float4 index 0..1023
        int r   = idx >> 4;
        int c4  = idx & 15;
        float4 v = ((const float4*)xp)[idx];
        *(float4*)&xs[r * XS + 4 + c4 * 4] = v;
    }
    #pragma unroll
    for (int i = 0; i < 3; ++i) {
        int idx = i * 256 + t;          // 0..767 pad zeroing
        int r   = idx / 12;
        int p   = idx % 12;
        int col = (p < 4) ? p : (p + 64);
        xs[r * XS + col] = 0.0f;
    }

    const float* wp  = dw_w + c * 49;
    const float bias = uniform_load(dw_b + c);

    __syncthreads();

    const int h  = t >> 2;
    const int w0 = (t & 3) << 4;

    float acc[16];
    #pragma unroll
    for (int j = 0; j < 16; ++j) acc[j] = bias;

    #pragma unroll
    for (int kh = 0; kh < 7; ++kh) {
        int hh = h + kh - 3;
        if (hh < 0 || hh >= HH) continue;
        // 7 block-uniform weights -> SGPRs (short live range)
        float wk[7];
        #pragma unroll
        for (int i = 0; i < 7; ++i) wk[i] = uniform_load(wp + kh * 7 + i);
        float r[24];
        const float* row = &xs[hh * XS + w0];
        #pragma unroll
        for (int j = 0; j < 6; ++j) *(float4*)&r[j * 4] = *(const float4*)&row[j * 4];
        #pragma unroll
        for (int kw = 0; kw < 7; ++kw)
            #pragma unroll
            for (int j = 0; j < 16; ++j)
                acc[j] = fmaf(r[j + kw + 1], wk[kw], acc[j]);
    }

    // pack 16 bf16 into two uint4 without a private union (SROA-safe)
    uint4 s0, s1;
    {
        __hip_bfloat162 p0 = __float22bfloat162_rn(make_float2(acc[0],  acc[1]));
        __hip_bfloat162 p1 = __float22bfloat162_rn(make_float2(acc[2],  acc[3]));
        __hip_bfloat162 p2 = __float22bfloat162_rn(make_float2(acc[4],  acc[5]));
        __hip_bfloat162 p3 = __float22bfloat162_rn(make_float2(acc[6],  acc[7]));
        __hip_bfloat162 p4 = __float22bfloat162_rn(make_float2(acc[8],  acc[9]));
        __hip_bfloat162 p5 = __float22bfloat162_rn(make_float2(acc[10], acc[11]));
        __hip_bfloat162 p6 = __float22bfloat162_rn(make_float2(acc[12], acc[13]));
        __hip_bfloat162 p7 = __float22bfloat162_rn(make_float2(acc[14], acc[15]));
        s0.x = *(unsigned*)&p0; s0.y = *(unsigned*)&p1;
        s0.z = *(unsigned*)&p2; s0.w = *(unsigned*)&p3;
        s1.x = *(unsigned*)&p4; s1.y = *(unsigned*)&p5;
        s1.z = *(unsigned*)&p6; s1.w = *(unsigned*)&p7;
    }
    // layout [n][h][c][w]
    unsigned short* op = cout + ((size_t)((n * 64 + h) * 128 + c) << 6) + w0;
    *(uint4*)op       = s0;
    *(uint4*)(op + 8) = s1;
}

// ---------------------------------------------------------------------------
// K2: LayerNorm + pointwise MLP (bf16 MFMA) + bias + residual, NCHW fp32 out
// r6 structure. NEW: XCD-contiguous block swizzle — XCD k owns the SAME
// n-range dwconv's XCD k wrote (conv reads become same-XCD L2 hits), and
// consecutive-h blocks (adjacent 256-B x/out chunks) share one L2.
// ---------------------------------------------------------------------------
#define HS 136   // sH row stride in shorts (272 B = 17 x 16 B)

__global__ __launch_bounds__(256, 4) void mlp_kernel(
    const unsigned short* __restrict__ conv,  // [n][h][c][w] bf16
    const float* __restrict__ gamma,          // 128
    const float* __restrict__ beta,           // 128
    const __hip_bfloat16* __restrict__ w1,    // 512 x 128 (bf16)
    const float* __restrict__ b1,             // 512
    const __hip_bfloat16* __restrict__ w2,    // 128 x 512 (bf16)
    const float* __restrict__ b2,             // 128
    const float* __restrict__ x,              // NCHW fp32
    float* __restrict__ out)                  // NCHW fp32
{
    __shared__ union {
        unsigned short xs[CCH * 64];   // staged [c][w] plane (16 KB)
        unsigned short h[64 * HS];     // H chunk [pos][d] (17 KB)
    } u;
    __shared__ float sPart[2][256];
    __shared__ float sMu[64], sRstd[64];

    const int t    = threadIdx.x;
    const int wave = t >> 6;
    const int lane = t & 63;
    const int q    = lane >> 4;          // 0..3
    const int ln   = lane & 15;          // 0..15
    const int wm   = (wave >> 1) * 32;   // wave M offset (0/32)
    const int wn   = (wave & 1) * 64;    // wave N offset (0/64)

    // bijective XCD swizzle: 2048 blocks = 8 XCDs x 256 contiguous rows
    const int rid = ((blockIdx.x & 7) << 8) | (blockIdx.x >> 3);
    const int n = rid >> 6;
    const int h = rid & 63;

    // ---- stage plane [c][w] (16 KB contiguous) into LDS ----
    {
        const uint4* src = (const uint4*)(conv + ((size_t)rid << 13));
        #pragma unroll
        for (int i = 0; i < 4; ++i) {
            int idx = i * 256 + t;                  // 16B chunk 0..1023
            uint4 v = src[idx];
            *(uint4*)&u.xs[idx * 8] = v;
        }
    }
    BAR_LGKM();

    // ---- LN stats: thread (cg = t>>6, w = t&63) ----
    {
        const int wI = t & 63, cg = t >> 6;
        float s = 0.f, s2 = 0.f;
        #pragma unroll
        for (int j = 0; j < 32; ++j) {
            float v = bf2f(u.xs[(cg * 32 + j) * 64 + wI]);
            s += v;
            s2 = fmaf(v, v, s2);
        }
        sPart[0][cg * 64 + wI] = s;
        sPart[1][cg * 64 + wI] = s2;
    }
    BAR_LGKM();
    if (t < 64) {
        float su = 0.f, sq = 0.f;
        #pragma unroll
        for (int g = 0; g < 4; ++g) { su += sPart[0][g * 64 + t]; sq += sPart[1][g * 64 + t]; }
        float mu  = su * (1.0f / 128.0f);
        float var = sq * (1.0f / 128.0f) - mu * mu;
        sMu[t]   = mu;
        sRstd[t] = 1.0f / sqrtf(var + EPS_LN);
    }
    BAR_LGKM();

    // ---- build normalized A-fragments in registers: A[m=pos][k=c] ----
    bf16x8 af[2][4];
    #pragma unroll
    for (int mt = 0; mt < 2; ++mt) {
        const int pos = wm + mt * 16 + ln;
        const float mu = sMu[pos], rs = sRstd[pos];
        #pragma unroll
        for (int kb = 0; kb < 4; ++kb) {
            const int c0 = kb * 32 + q * 8;
            float4 g0  = *(const float4*)(gamma + c0);
            float4 g1  = *(const float4*)(gamma + c0 + 4);
            float4 be0 = *(const float4*)(beta + c0);
            float4 be1 = *(const float4*)(beta + c0 + 4);
            float gv[8] = {g0.x, g0.y, g0.z, g0.w, g1.x, g1.y, g1.z, g1.w};
            float bv[8] = {be0.x, be0.y, be0.z, be0.w, be1.x, be1.y, be1.z, be1.w};
            bf16x8 a;
            #pragma unroll
            for (int j = 0; j < 8; ++j) {
                float v = bf2f(u.xs[(c0 + j) * 64 + pos]);
                float r = (v - mu) * rs * gv[j] + bv[j];
                a[j] = (short)f2bf(r);
            }
            af[mt][kb] = a;
        }
    }

    f32x4 oacc[2][4];
    #pragma unroll
    for (int mt = 0; mt < 2; ++mt)
        #pragma unroll
        for (int ct = 0; ct < 4; ++ct) oacc[mt][ct] = (f32x4){0.f, 0.f, 0.f, 0.f};

    for (int dc = 0; dc < 4; ++dc) {
        const int d0 = dc * 128;

        // stage 1: Hc = Y @ W1^T (A from regs, B from global/L2)
        f32x4 hacc[2][4];
        #pragma unroll
        for (int mt = 0; mt < 2; ++mt)
            #pragma unroll
            for (int dt = 0; dt < 4; ++dt) hacc[mt][dt] = (f32x4){0.f, 0.f, 0.f, 0.f};

        #pragma unroll
        for (int kb = 0; kb < 4; ++kb) {
            bf16x8 bw[4];
            #pragma unroll
            for (int dt = 0; dt < 4; ++dt) {
                int d = d0 + wn + dt * 16 + ln;
                bw[dt] = *(const bf16x8*)(w1 + (size_t)d * 128 + kb * 32 + q * 8);
            }
            #pragma unroll
            for (int mt = 0; mt < 2; ++mt)
                #pragma unroll
                for (int dt = 0; dt < 4; ++dt)
                    hacc[mt][dt] = __builtin_amdgcn_mfma_f32_16x16x32_bf16(
                        af[mt][kb], bw[dt], hacc[mt][dt], 0, 0, 0);
        }

        BAR_LGKM();   // prev readers of u (xs A-build or stage2) done

        // bias + relu + bf16 -> sH
        #pragma unroll
        for (int dt = 0; dt < 4; ++dt) {
            const int dl = wn + dt * 16 + ln;
            const float b1v = b1[d0 + dl];
            #pragma unroll
            for (int mt = 0; mt < 2; ++mt) {
                #pragma unroll
                for (int r = 0; r < 4; ++r) {
                    float v = fmaxf(hacc[mt][dt][r] + b1v, 0.0f);
                    u.h[(wm + mt * 16 + q * 4 + r) * HS + dl] = f2bf(v);
                }
            }
        }
        BAR_LGKM();

        // stage 2: O += H @ W2_chunk^T
        #pragma unroll
        for (int kb = 0; kb < 4; ++kb) {
            bf16x8 ah[2];
            #pragma unroll
            for (int mt = 0; mt < 2; ++mt)
                ah[mt] = *(const bf16x8*)&u.h[(wm + mt * 16 + ln) * HS + kb * 32 + q * 8];
            bf16x8 bw2[4];
            #pragma unroll
            for (int ct = 0; ct < 4; ++ct) {
                int c = wn + ct * 16 + ln;
                bw2[ct] = *(const bf16x8*)(w2 + (size_t)c * DBOT + d0 + kb * 32 + q * 8);
            }
            #pragma unroll
            for (int mt = 0; mt < 2; ++mt)
                #pragma unroll
                for (int ct = 0; ct < 4; ++ct)
                    oacc[mt][ct] = __builtin_amdgcn_mfma_f32_16x16x32_bf16(
                        ah[mt], bw2[ct], oacc[mt][ct], 0, 0, 0);
        }
    }

    // ---- epilogue: direct float4 stores, out = O + b2 + x (NCHW) ----
    #pragma unroll
    for (int ct = 0; ct < 4; ++ct) {
        const int c = wn + ct * 16 + ln;
        const float b2v = b2[c];
        #pragma unroll
        for (int mt = 0; mt < 2; ++mt) {
            size_t base = ((size_t)(n * CCH + c) << 12) + (h << 6) + wm + mt * 16 + q * 4;
            float4 xr = *(const float4*)(x + base);
            float4 o;
            o.x = oacc[mt][ct][0] + b2v + xr.x;
            o.y = oacc[mt][ct][1] + b2v + xr.y;
            o.z = oacc[mt][ct][2] + b2v + xr.z;
            o.w = oacc[mt][ct][3] + b2v + xr.w;
            *(float4*)(out + base) = o;
        }
    }
}

// ---------------------------------------------------------------------------
extern "C" void kernel_launch(void* const* d_in, const int* in_sizes, int n_in,
                              void* d_out, int out_size, void* d_ws, size_t ws_size,
                              hipStream_t stream)
{
    const float* x     = (const float*)d_in[0];
    const float* dw_w  = (const float*)d_in[1];
    const float* dw_b  = (const float*)d_in[2];
    const float* gamma = (const float*)d_in[3];
    const float* beta  = (const float*)d_in[4];
    const float* pw1_w = (const float*)d_in[5];
    const float* pw1_b = (const float*)d_in[6];
    const float* pw2_w = (const float*)d_in[7];
    const float* pw2_b = (const float*)d_in[8];
    float* out = (float*)d_out;

    char* ws = (char*)d_ws;
    unsigned short* convb = (unsigned short*)ws;                       // 32 MiB
    __hip_bfloat16* w1b   = (__hip_bfloat16*)(ws + (size_t)33554432);  // 128 KiB
    __hip_bfloat16* w2b   = (__hip_bfloat16*)(ws + (size_t)33554432 + 131072);

    wcvt_kernel<<<256, 256, 0, stream>>>(pw1_w, pw2_w, w1b, w2b);
    dwconv_kernel<<<NB * CCH, 256, 0, stream>>>(x, dw_w, dw_b, convb);
    mlp_kernel<<<NB * HH, 256, 0, stream>>>(convb, gamma, beta, w1b, pw1_b, w2b, pw2_b, x, out);
}